// Round 5
// baseline (216.413 us; speedup 1.0000x reference)
//
#include <hip/hip_runtime.h>
#include <hip/hip_fp16.h>
#include <math.h>

#define TEX_W 2048
#define TEX_H 2048
#define TEX_MAX 2047

typedef float f32x4 __attribute__((ext_vector_type(4)));
typedef float f32x2 __attribute__((ext_vector_type(2)));
typedef unsigned short u16;
typedef u16 u16x8 __attribute__((ext_vector_type(8)));

__device__ __forceinline__ float fast_tanh(float x) {
    // tanh(x) = 1 - 2/(exp(2x)+1); saturates correctly at +-inf
    float e = __expf(2.0f * x);
    return 1.0f - 2.0f * __builtin_amdgcn_rcpf(e + 1.0f);
}
__device__ __forceinline__ u16 f2h(float x) {
    return __half_as_ushort(__float2half_rn(x));
}
__device__ __forceinline__ float h2f(u16 x) {
    return __half2float(__ushort_as_half(x));
}

// Quad table: one 32 B entry per texel (u,v), two u16x8 halves:
//   lo = {c00.rgb, 0, c01.rgb, 0}   (c01 = t[u][v+1], col clamped)
//   hi = {c10.rgb, 0, c11.rgb, 0}   (row clamped)
// 2048*2048*32 B = 128 MiB; entries 32 B aligned -> exactly one 64 B line
// per sample. Layout is byte-identical to the R4 (proven) table.
__global__ void __launch_bounds__(256)
build_quad(const float* __restrict__ tex, u16x8* __restrict__ q) {
    int id = blockIdx.x * blockDim.x + threadIdx.x;  // [0, 2048*2048)
    int u = id >> 11, v = id & TEX_MAX;
    int up = (u < TEX_MAX) ? u + 1 : TEX_MAX;
    int vp = (v < TEX_MAX) ? v + 1 : TEX_MAX;
    const float* t00 = tex + ((size_t)u  * TEX_W + v ) * 3;
    const float* t01 = tex + ((size_t)u  * TEX_W + vp) * 3;
    const float* t10 = tex + ((size_t)up * TEX_W + v ) * 3;
    const float* t11 = tex + ((size_t)up * TEX_W + vp) * 3;
    u16x8 lo = {f2h(t00[0]), f2h(t00[1]), f2h(t00[2]), 0,
                f2h(t01[0]), f2h(t01[1]), f2h(t01[2]), 0};
    u16x8 hi = {f2h(t10[0]), f2h(t10[1]), f2h(t10[2]), 0,
                f2h(t11[0]), f2h(t11[1]), f2h(t11[2]), 0};
    q[(size_t)2 * id]     = lo;
    q[(size_t)2 * id + 1] = hi;
}

// 4 samples per thread; all 8 entry loads issued before any blend.
__global__ void __launch_bounds__(256)
sample_quad4(const f32x4* __restrict__ uvs4, const u16x8* __restrict__ q,
             float* __restrict__ out, int n4) {
    int i = blockIdx.x * blockDim.x + threadIdx.x;
    if (i >= n4) return;
    f32x4 uvA = __builtin_nontemporal_load(uvs4 + (size_t)2 * i);
    f32x4 uvB = __builtin_nontemporal_load(uvs4 + (size_t)2 * i + 1);
    float ux[4] = {uvA.x, uvA.z, uvB.x, uvB.z};
    float vx[4] = {uvA.y, uvA.w, uvB.y, uvB.w};
    float a[4], b[4];
    bool ru[4], cv[4];
    size_t base[4];
#pragma unroll
    for (int s = 0; s < 4; ++s) {
        // exact reference op order: ((uv + 1) * 0.5) * (W-1)
        float u = (ux[s] + 1.0f) * 0.5f * (float)(TEX_W - 1);
        float v = (vx[s] + 1.0f) * 0.5f * (float)(TEX_H - 1);
        float fu0 = floorf(u), fv0 = floorf(v);
        int u0 = (int)fu0, v0 = (int)fv0;
        int u1 = (int)ceilf(u), v1 = (int)ceilf(v);  // exactly as reference
        a[s] = u - fu0;
        b[s] = v - fv0;
        ru[s] = (u1 > u0);
        cv[s] = (v1 > v0);
        base[s] = (size_t)((u0 << 11) + v0) * 2;
    }
    u16x8 lo[4], hi[4];
#pragma unroll
    for (int s = 0; s < 4; ++s) {
        lo[s] = q[base[s]];
        hi[s] = q[base[s] + 1];
    }
    float o[12];
#pragma unroll
    for (int s = 0; s < 4; ++s) {
        float aa = a[s], bb = b[s];
        float a1 = 1.0f - aa, b1 = 1.0f - bb;
#pragma unroll
        for (int c = 0; c < 3; ++c) {
            float c00 = h2f(lo[s][c]);
            float c01 = cv[s] ? h2f(lo[s][4 + c]) : c00;               // t[u0][v1]
            float c10 = ru[s] ? h2f(hi[s][c]) : c00;                   // t[u1][v0]
            float c11 = ru[s] ? (cv[s] ? h2f(hi[s][4 + c]) : c10) : c01;
            float col = (c00 * aa + c10 * a1) * bb + (c01 * aa + c11 * a1) * b1;
            o[s * 3 + c] = fast_tanh(col);
        }
    }
    f32x4* ob = (f32x4*)(out + (size_t)i * 12);
    f32x4 p0 = {o[0], o[1], o[2], o[3]};
    f32x4 p1 = {o[4], o[5], o[6], o[7]};
    f32x4 p2 = {o[8], o[9], o[10], o[11]};
    __builtin_nontemporal_store(p0, ob);
    __builtin_nontemporal_store(p1, ob + 1);
    __builtin_nontemporal_store(p2, ob + 2);
}

// ---------------- fallback: fp32 direct (round-1, proven) ----------------
__global__ void __launch_bounds__(256)
difftex_f32(const float2* __restrict__ uvs, const float* __restrict__ tex,
            float* __restrict__ out, int n) {
    int i = blockIdx.x * blockDim.x + threadIdx.x;
    if (i >= n) return;
    float2 uv = uvs[i];
    float u = (uv.x + 1.0f) * 0.5f * (float)(TEX_W - 1);
    float v = (uv.y + 1.0f) * 0.5f * (float)(TEX_H - 1);
    float fu0 = floorf(u), fv0 = floorf(v);
    int u0 = (int)fu0, v0 = (int)fv0;
    int u1 = (int)ceilf(u), v1 = (int)ceilf(v);
    float a = u - fu0, b = v - fv0;
    float a1 = 1.0f - a, b1 = 1.0f - b;
    const float* p00 = tex + ((long)u0 * TEX_W + v0) * 3;
    const float* p10 = tex + ((long)u1 * TEX_W + v0) * 3;
    const float* p01 = tex + ((long)u0 * TEX_W + v1) * 3;
    const float* p11 = tex + ((long)u1 * TEX_W + v1) * 3;
    long base = (long)i * 3;
#pragma unroll
    for (int c = 0; c < 3; ++c) {
        float col = (p00[c] * a + p10[c] * a1) * b + (p01[c] * a + p11[c] * a1) * b1;
        out[base + c] = fast_tanh(col);
    }
}

extern "C" void kernel_launch(void* const* d_in, const int* in_sizes, int n_in,
                              void* d_out, int out_size, void* d_ws, size_t ws_size,
                              hipStream_t stream) {
    const float* tex = (const float*)d_in[1];
    float* out = (float*)d_out;
    int n = in_sizes[0] / 2;  // sample count

    const size_t quad_bytes = (size_t)TEX_W * TEX_H * 32;  // 128 MiB
    const int entries = TEX_W * TEX_H;

    if (ws_size >= quad_bytes && (n & 3) == 0) {
        build_quad<<<entries / 256, 256, 0, stream>>>(tex, (u16x8*)d_ws);
        int n4 = n / 4;
        sample_quad4<<<(n4 + 255) / 256, 256, 0, stream>>>(
            (const f32x4*)d_in[0], (const u16x8*)d_ws, out, n4);
    } else {
        difftex_f32<<<(n + 255) / 256, 256, 0, stream>>>(
            (const float2*)d_in[0], tex, out, n);
    }
}

// Round 6
// 206.584 us; speedup vs baseline: 1.0476x; 1.0476x over previous
//
#include <hip/hip_runtime.h>
#include <hip/hip_fp16.h>
#include <math.h>

#define TEX_W 2048
#define TEX_H 2048
#define TEX_MAX 2047

typedef float f32x4 __attribute__((ext_vector_type(4)));
typedef float f32x2 __attribute__((ext_vector_type(2)));
typedef unsigned short u16;
typedef u16 u16x4 __attribute__((ext_vector_type(4)));

__device__ __forceinline__ float fast_tanh(float x) {
    // tanh(x) = 1 - 2/(exp(2x)+1); saturates correctly at +-inf
    float e = __expf(2.0f * x);
    return 1.0f - 2.0f * __builtin_amdgcn_rcpf(e + 1.0f);
}
__device__ __forceinline__ u16 f2h(float x) {
    return __half_as_ushort(__float2half_rn(x));
}
__device__ __forceinline__ float h2f(u16 x) {
    return __half2float(__ushort_as_half(x));
}

// Quad table: one 32 B entry per texel (u,v), laid out as 4 x u16x4:
//   sub 0: t[u][v]        (c00)
//   sub 1: t[u][v+1]      (c01; col clamped at edge)
//   sub 2: t[u+1][v]      (c10; row clamped at edge)
//   sub 3: t[u+1][v+1]    (c11)
// 2048*2048*32 B = 128 MiB. Entry is 32 B aligned -> any sample reads
// exactly ONE 64 B cache line. This is the measured byte floor:
// 8.39M samples x 64 B = 537 MB gather traffic, at the ~3.8 TB/s
// random-line fabric ceiling (R2/R4/R5 all plateau there).
__global__ void __launch_bounds__(256)
build_quad(const float* __restrict__ tex, u16x4* __restrict__ q) {
    int id = blockIdx.x * blockDim.x + threadIdx.x;  // [0, 2048*2048)
    int u = id >> 11, v = id & TEX_MAX;
    int up = (u < TEX_MAX) ? u + 1 : TEX_MAX;
    int vp = (v < TEX_MAX) ? v + 1 : TEX_MAX;
    const float* t00 = tex + ((size_t)u  * TEX_W + v ) * 3;
    const float* t01 = tex + ((size_t)u  * TEX_W + vp) * 3;
    const float* t10 = tex + ((size_t)up * TEX_W + v ) * 3;
    const float* t11 = tex + ((size_t)up * TEX_W + vp) * 3;
    u16x4 e0 = {f2h(t00[0]), f2h(t00[1]), f2h(t00[2]), 0};
    u16x4 e1 = {f2h(t01[0]), f2h(t01[1]), f2h(t01[2]), 0};
    u16x4 e2 = {f2h(t10[0]), f2h(t10[1]), f2h(t10[2]), 0};
    u16x4 e3 = {f2h(t11[0]), f2h(t11[1]), f2h(t11[2]), 0};
    size_t base = (size_t)id * 4;
    q[base + 0] = e0;
    q[base + 1] = e1;
    q[base + 2] = e2;
    q[base + 3] = e3;
}

__device__ __forceinline__ void quad_one(float x, float y,
                                         const u16x4* __restrict__ q, float* o) {
    // exact reference op order: ((uv + 1) * 0.5) * (W-1)
    float u = (x + 1.0f) * 0.5f * (float)(TEX_W - 1);
    float v = (y + 1.0f) * 0.5f * (float)(TEX_H - 1);
    float fu0 = floorf(u), fv0 = floorf(v);
    int u0 = (int)fu0, v0 = (int)fv0;
    int u1 = (int)ceilf(u), v1 = (int)ceilf(v);  // exactly as reference
    float a = u - fu0, b = v - fv0;
    float a1 = 1.0f - a, b1 = 1.0f - b;
    bool ru = (u1 > u0);  // row u1 distinct from u0
    bool cv = (v1 > v0);  // col v1 distinct from v0
    size_t base = (size_t)((u0 << 11) + v0) * 4;
    u16x4 e0 = q[base + 0];
    u16x4 e1 = q[base + 1];
    u16x4 e2 = q[base + 2];
    u16x4 e3 = q[base + 3];
#pragma unroll
    for (int c = 0; c < 3; ++c) {
        float c00 = h2f(e0[c]);
        float c01 = cv ? h2f(e1[c]) : c00;               // t[u0][v1]
        float c10 = ru ? h2f(e2[c]) : c00;               // t[u1][v0]
        float c11 = ru ? (cv ? h2f(e3[c]) : c10) : c01;  // t[u1][v1]
        float col = (c00 * a + c10 * a1) * b + (c01 * a + c11 * a1) * b1;
        o[c] = fast_tanh(col);
    }
}

// 2 samples per thread (R4 structure — measured fastest: 177 us)
__global__ void __launch_bounds__(256)
sample_quad(const f32x4* __restrict__ uvs2, const u16x4* __restrict__ q,
            float* __restrict__ out, int n2) {
    int i = blockIdx.x * blockDim.x + threadIdx.x;
    if (i >= n2) return;
    f32x4 uv2 = __builtin_nontemporal_load(uvs2 + i);
    float o[6];
    quad_one(uv2.x, uv2.y, q, o);
    quad_one(uv2.z, uv2.w, q, o + 3);
    f32x2* ob = (f32x2*)(out + (size_t)i * 6);
    f32x2 p0 = {o[0], o[1]}, p1 = {o[2], o[3]}, p2 = {o[4], o[5]};
    __builtin_nontemporal_store(p0, ob);
    __builtin_nontemporal_store(p1, ob + 1);
    __builtin_nontemporal_store(p2, ob + 2);
}

// ---------------- fallback: fp32 direct (round-1, proven) ----------------
__global__ void __launch_bounds__(256)
difftex_f32(const float2* __restrict__ uvs, const float* __restrict__ tex,
            float* __restrict__ out, int n) {
    int i = blockIdx.x * blockDim.x + threadIdx.x;
    if (i >= n) return;
    float2 uv = uvs[i];
    float u = (uv.x + 1.0f) * 0.5f * (float)(TEX_W - 1);
    float v = (uv.y + 1.0f) * 0.5f * (float)(TEX_H - 1);
    float fu0 = floorf(u), fv0 = floorf(v);
    int u0 = (int)fu0, v0 = (int)fv0;
    int u1 = (int)ceilf(u), v1 = (int)ceilf(v);
    float a = u - fu0, b = v - fv0;
    float a1 = 1.0f - a, b1 = 1.0f - b;
    const float* p00 = tex + ((long)u0 * TEX_W + v0) * 3;
    const float* p10 = tex + ((long)u1 * TEX_W + v0) * 3;
    const float* p01 = tex + ((long)u0 * TEX_W + v1) * 3;
    const float* p11 = tex + ((long)u1 * TEX_W + v1) * 3;
    long base = (long)i * 3;
#pragma unroll
    for (int c = 0; c < 3; ++c) {
        float col = (p00[c] * a + p10[c] * a1) * b + (p01[c] * a + p11[c] * a1) * b1;
        out[base + c] = fast_tanh(col);
    }
}

extern "C" void kernel_launch(void* const* d_in, const int* in_sizes, int n_in,
                              void* d_out, int out_size, void* d_ws, size_t ws_size,
                              hipStream_t stream) {
    const float* tex = (const float*)d_in[1];
    float* out = (float*)d_out;
    int n = in_sizes[0] / 2;  // sample count

    const size_t quad_bytes = (size_t)TEX_W * TEX_H * 32;  // 128 MiB
    const int entries = TEX_W * TEX_H;

    if (ws_size >= quad_bytes && (n & 1) == 0) {
        build_quad<<<entries / 256, 256, 0, stream>>>(tex, (u16x4*)d_ws);
        int n2 = n / 2;
        sample_quad<<<(n2 + 255) / 256, 256, 0, stream>>>(
            (const f32x4*)d_in[0], (const u16x4*)d_ws, out, n2);
    } else {
        difftex_f32<<<(n + 255) / 256, 256, 0, stream>>>(
            (const float2*)d_in[0], tex, out, n);
    }
}